// Round 7
// baseline (271.068 us; speedup 1.0000x reference)
//
#include <hip/hip_runtime.h>
#include <math.h>

#define TLEN 2048
#define T2   4096
#define H2   2048
#define NBLK 512          // fused kernel: 1 channel/block, 2 blocks/CU co-resident
#define EPS32 1.1920928955078125e-07
#define TOLV 5e-5
#define A0   (-1.5339807878856412e-3f)   // -2*pi/4096
// bijective LDS swizzle: stride-16 writes and stride-256 reads conflict-free
#define PHI(i) ((i) ^ (((i) >> 4) & 15))

__device__ __forceinline__ float2 cmulf(float2 a, float2 b){
  return make_float2(a.x * b.x - a.y * b.y, a.x * b.y + a.y * b.x);
}

// radix-4 butterfly in regs; s=+1 forward (W4=-i), s=-1 inverse (W4=+i)
__device__ __forceinline__ void dft4(float2& x0, float2& x1, float2& x2, float2& x3, float s){
  float t0x = x0.x + x2.x, t0y = x0.y + x2.y;
  float t1x = x0.x - x2.x, t1y = x0.y - x2.y;
  float t2x = x1.x + x3.x, t2y = x1.y + x3.y;
  float t3x = x1.x - x3.x, t3y = x1.y - x3.y;
  float r3x = s * t3y, r3y = -s * t3x;        // (-i*s) * t3
  x0 = make_float2(t0x + t2x, t0y + t2y);
  x1 = make_float2(t1x + r3x, t1y + r3y);
  x2 = make_float2(t0x - t2x, t0y - t2y);
  x3 = make_float2(t1x - r3x, t1y - r3y);
}

// 16-point FFT in registers: DFT4 over m1, W16^(u0*m0) twiddles, DFT4 over m0.
// Input v[m]=x[m] natural; output X[u0+4*u1] lands in v[4*u0+u1].
__device__ __forceinline__ void fft16r(float2* v, float s){
  const float C[10] = {1.f, 0.92387953251128674f, 0.70710678118654752f, 0.38268343236508977f,
                       0.f, 0.f, -0.70710678118654752f, 0.f, 0.f, -0.92387953251128674f};
  const float S[10] = {0.f, -0.38268343236508977f, -0.70710678118654752f, -0.92387953251128674f,
                       -1.f, 0.f, -0.70710678118654752f, 0.f, 0.f, 0.38268343236508977f};
  #pragma unroll
  for (int m0 = 0; m0 < 4; ++m0) dft4(v[m0], v[4 + m0], v[8 + m0], v[12 + m0], s);
  #pragma unroll
  for (int u0 = 1; u0 < 4; ++u0)
    #pragma unroll
    for (int m0 = 1; m0 < 4; ++m0){
      int k = u0 * m0;
      v[(u0 << 2) + m0] = cmulf(v[(u0 << 2) + m0], make_float2(C[k], s * S[k]));
    }
  #pragma unroll
  for (int u0 = 0; u0 < 4; ++u0)
    dft4(v[u0 << 2], v[(u0 << 2) + 1], v[(u0 << 2) + 2], v[(u0 << 2) + 3], s);
}

// 4096-pt FFT: 3 radix-16 Stockham stages; twiddles via HW sin/cos (radians).
// Input bufA (PHI layout) -> result bufB (PHI layout, natural order).
// s=+1: e^{-i..} fwd; s=-1: e^{+i..} inv. Trailing __syncthreads included.
__device__ __forceinline__ void fft4096(float2* bufA, float2* bufB, float s){
  const int tid = threadIdx.x;
  const float a0 = s * A0;            // s * (-2pi/4096)
  float2 v[16];
  // ---- stage 0: L=1, p=tid; twiddle W4096^{u*tid} ----
  #pragma unroll
  for (int m = 0; m < 16; ++m) v[m] = bufA[PHI(tid + (m << 8))];
  fft16r(v, s);
  #pragma unroll
  for (int u0 = 0; u0 < 4; ++u0)
    #pragma unroll
    for (int u1 = 0; u1 < 4; ++u1){
      int u = u0 + (u1 << 2);
      float2 X = v[(u0 << 2) + u1];
      if (u){
        float ang = a0 * (float)(u * tid);          // |u*tid| <= 3825, exact fp32
        X = cmulf(X, make_float2(__cosf(ang), __sinf(ang)));
      }
      bufB[PHI((tid << 4) + u)] = X;
    }
  __syncthreads();
  // ---- stage 1: L=16, p=tid>>4, q=tid&15; twiddle W4096^{16*u*p} ----
  #pragma unroll
  for (int m = 0; m < 16; ++m) v[m] = bufB[PHI(tid + (m << 8))];
  fft16r(v, s);
  {
    const int p = tid >> 4, q = tid & 15;
    const float a1 = a0 * 16.0f;
    #pragma unroll
    for (int u0 = 0; u0 < 4; ++u0)
      #pragma unroll
      for (int u1 = 0; u1 < 4; ++u1){
        int u = u0 + (u1 << 2);
        float2 X = v[(u0 << 2) + u1];
        if (u){
          float ang = a1 * (float)(u * p);          // |u*p| <= 225
          X = cmulf(X, make_float2(__cosf(ang), __sinf(ang)));
        }
        bufA[PHI(q + (((p << 4) + u) << 4))] = X;
      }
  }
  __syncthreads();
  // ---- stage 2: L=256, q=tid; no twiddle ----
  #pragma unroll
  for (int m = 0; m < 16; ++m) v[m] = bufA[PHI(tid + (m << 8))];
  fft16r(v, s);
  #pragma unroll
  for (int u0 = 0; u0 < 4; ++u0)
    #pragma unroll
    for (int u1 = 0; u1 < 4; ++u1){
      int u = u0 + (u1 << 2);
      bufB[PHI(tid + (u << 8))] = v[(u0 << 2) + u1];
    }
  __syncthreads();
}

// ---- prep: coalesced transpose x:(B,T,C)->(c,t); zero stats + barrier words ----
__global__ void k_prep(const float* __restrict__ x, float* __restrict__ xr,
                       double* __restrict__ accs, unsigned* __restrict__ bar){
  const int blk = blockIdx.x, tid = threadIdx.x;
  if (blk == 0){
    if (tid < 64) accs[tid] = 0.0;                  // 4 slots x 16 doubles (128B pad)
    if (tid >= 64 && tid < 192) bar[tid - 64] = 0u; // 4 x {counter,flag} padded
  }
  __shared__ float tile[64][65];
  const int b  = blk >> 5;
  const int t0 = (blk & 31) << 6;
  const int lo = tid & 63, r0 = tid >> 6;
  for (int pass = 0; pass < 16; ++pass){
    int tt = r0 + (pass << 2);
    tile[tt][lo] = x[((size_t)(b * TLEN + t0 + tt)) * 64 + lo];  // lo = ch, coalesced
  }
  __syncthreads();
  for (int pass = 0; pass < 16; ++pass){
    int c2 = r0 + (pass << 2);
    xr[((size_t)(b * 64 + c2)) * TLEN + t0 + lo] = tile[lo][c2]; // lo = t, coalesced
  }
}

// ---- load mirror-extended signal into bufA (PHI layout) ----
__device__ __forceinline__ void mirror_load(const float* __restrict__ f, float2* bufA){
  const int tid = threadIdx.x;
  #pragma unroll
  for (int pp = 0; pp < 16; ++pp){
    int i = tid + (pp << 8);
    int s = (i < 1024) ? (1023 - i) : ((i < 3072) ? (i - 1024) : (5119 - i));
    bufA[PHI(i)] = make_float2(f[s], 0.0f);
  }
}

// ---- fused VMD: fwd FFT + 5 iterations (u,F in VGPRs, grid barriers) + IFFT ----
// 512 blocks x 256 thr x 66KB LDS -> 2 blocks/CU always fit (132<=160KB, 8<=32
// waves, 256 VGPR x 2 waves = per-SIMD budget) => all 512 blocks co-resident.
__launch_bounds__(256, 2)
__global__ void k_vmd(const float* __restrict__ xr,
                      double* __restrict__ accs, unsigned* __restrict__ bar,
                      float* __restrict__ xl_s){
  __shared__ float2 bufA[T2];
  __shared__ float2 bufB[T2];
  __shared__ double red[40];
  const int tid = threadIdx.x;
  const int wave = tid >> 6, lane = tid & 63;
  const int c = blockIdx.x;

  // ---- forward FFT, spectrum kept in registers ----
  float2 F[8];
  mirror_load(xr + (size_t)c * TLEN, bufA);
  __syncthreads();
  fft4096(bufA, bufB, 1.0f);
  #pragma unroll
  for (int pp = 0; pp < 8; ++pp) F[pp] = bufB[PHI(tid + (pp << 8))];

  // ---- VMD state in registers ----
  float2 u[4][8];
  #pragma unroll
  for (int k = 0; k < 4; ++k)
    #pragma unroll
    for (int pp = 0; pp < 8; ++pp) u[k][pp] = make_float2(0.f, 0.f);

  float om[4] = {0.0f, 0.125f, 0.25f, 0.375f};
  bool active = true;

  for (int it = 0; it < 4; ++it){         // reference iterations 1..4 (with stats)
    if (active){
      double aFP[4] = {0,0,0,0}, aP[4] = {0,0,0,0}, aD = 0.0;
      #pragma unroll
      for (int pp = 0; pp < 8; ++pp){
        int j = tid + (pp << 8);
        float fj = (float)j * (1.0f / 4096.0f);
        float Fx = F[pp].x, Fy = F[pp].y;
        float sx = u[0][pp].x + u[1][pp].x + u[2][pp].x + u[3][pp].x;
        float sy = u[0][pp].y + u[1][pp].y + u[2][pp].y + u[3][pp].y;
        #pragma unroll
        for (int k = 0; k < 4; ++k){
          float ox = sx - u[k][pp].x, oy = sy - u[k][pp].y;
          float d = fj - om[k];
          float den = 1.0f + 2000.0f * d * d;
          float nx = (Fx - ox) / den, ny = (Fy - oy) / den;
          float pw = nx * nx + ny * ny;
          aFP[k] += (double)(fj * pw);
          aP[k]  += (double)pw;
          float ddx = nx - u[k][pp].x, ddy = ny - u[k][pp].y;
          aD += (double)(ddx * ddx + ddy * ddy);
          u[k][pp] = make_float2(nx, ny);
          sx = ox + nx; sy = oy + ny;
        }
      }
      double acc9[9] = {aFP[0],aFP[1],aFP[2],aFP[3],aP[0],aP[1],aP[2],aP[3],aD};
      #pragma unroll
      for (int i = 0; i < 9; ++i){
        double v = acc9[i];
        for (int off = 32; off; off >>= 1) v += __shfl_down(v, off);
        if (lane == 0) red[i * 4 + wave] = v;
      }
      __syncthreads();
      if (tid < 9)
        atomicAdd(&accs[it * 16 + tid],
                  red[tid*4+0] + red[tid*4+1] + red[tid*4+2] + red[tid*4+3]);
    }
    // ---- grid barrier (always; `active` is grid-uniform) ----
    if (tid == 0){
      __threadfence();
      unsigned* cnt  = bar + it * 32;
      unsigned* flag = bar + it * 32 + 16;
      unsigned old = __hip_atomic_fetch_add(cnt, 1u, __ATOMIC_ACQ_REL,
                                            __HIP_MEMORY_SCOPE_AGENT);
      if (old == NBLK - 1u){
        __hip_atomic_store(flag, 1u, __ATOMIC_RELEASE, __HIP_MEMORY_SCOPE_AGENT);
      } else {
        while (__hip_atomic_load(flag, __ATOMIC_ACQUIRE,
                                 __HIP_MEMORY_SCOPE_AGENT) == 0u)
          __builtin_amdgcn_s_sleep(8);
      }
    }
    __syncthreads();
    if (active){
      if (tid == 0){
        #pragma unroll
        for (int i = 0; i < 9; ++i)
          red[i] = __hip_atomic_load(&accs[it * 16 + i], __ATOMIC_RELAXED,
                                     __HIP_MEMORY_SCOPE_AGENT);
      }
      __syncthreads();
      #pragma unroll
      for (int k = 0; k < 4; ++k) om[k] = (float)(red[k] / red[4 + k]);
      double ud = red[8] * (1.0 / 4096.0) + EPS32;
      active = (ud > TOLV);
    }
    __syncthreads();
  }

  // ---- reference iteration 5: only mode-0 matters downstream ----
  if (active){
    #pragma unroll
    for (int pp = 0; pp < 8; ++pp){
      int j = tid + (pp << 8);
      float fj = (float)j * (1.0f / 4096.0f);
      float ox = u[1][pp].x + u[2][pp].x + u[3][pp].x;
      float oy = u[1][pp].y + u[2][pp].y + u[3][pp].y;
      float d = fj - om[0];
      float den = 1.0f + 2000.0f * d * d;
      u[0][pp] = make_float2((F[pp].x - ox) / den, (F[pp].y - oy) / den);
    }
  }

  // ---- Hermitian build (reference quirks) + inverse FFT ----
  __syncthreads();
  #pragma unroll
  for (int pp = 0; pp < 8; ++pp){
    int j = tid + (pp << 8);
    float2 v = u[0][pp];
    if (j == 0){
      bufA[PHI(0)] = make_float2(v.x, -v.y);          // S[0] = conj(U[0])
    } else {
      bufA[PHI(j)]      = v;                          // S[j] = U[j]
      bufA[PHI(T2 - j)] = make_float2(v.x, -v.y);     // S[4096-j] = conj(U[j])
    }
    if (j == H2 - 1) bufA[PHI(H2)] = make_float2(v.x, -v.y); // S[2048]=conj(U[2047])
  }
  __syncthreads();
  fft4096(bufA, bufB, -1.0f);
  const float scale = 1.0f / (float)T2;
  float* out = xl_s + (size_t)c * TLEN;
  #pragma unroll
  for (int pp = 0; pp < 8; ++pp){
    int t = tid + (pp << 8);
    out[t] = bufB[PHI(1024 + t)].x * scale;
  }
}

// ---- transpose back + x_h = x - x_l ----
__global__ void k_tout(const float* __restrict__ x, const float* __restrict__ xl_s,
                       float* __restrict__ xh, float* __restrict__ xl){
  __shared__ float tile[64][65];
  int blk = blockIdx.x;
  int b  = blk >> 5;
  int t0 = (blk & 31) << 6;
  int lo = threadIdx.x & 63;
  int r0 = threadIdx.x >> 6;
  for (int pass = 0; pass < 16; ++pass){
    int c2 = r0 + (pass << 2);
    tile[c2][lo] = xl_s[((size_t)(b * 64 + c2)) * TLEN + t0 + lo];
  }
  __syncthreads();
  for (int pass = 0; pass < 16; ++pass){
    int tt = r0 + (pass << 2);
    size_t oi = ((size_t)(b * TLEN + t0 + tt)) * 64 + lo;
    float xlv = tile[lo][tt];
    float xv  = x[oi];
    xh[oi] = xv - xlv;
    xl[oi] = xlv;
  }
}

extern "C" void kernel_launch(void* const* d_in, const int* in_sizes, int n_in,
                              void* d_out, int out_size, void* d_ws, size_t ws_size,
                              hipStream_t stream){
  const float* x = (const float*)d_in[0];
  float* out_xh = (float*)d_out;
  float* out_xl = out_xh + (size_t)8 * TLEN * 64;

  char* ws = (char*)d_ws;
  float*    xr   = (float*)ws;                               // 4 MiB
  float*    xl_s = (float*)(ws + ((size_t)4 << 20));         // 4 MiB
  double*   accs = (double*)(ws + ((size_t)8 << 20));        // 64 doubles (padded)
  unsigned* bar  = (unsigned*)(ws + ((size_t)8 << 20) + 512);   // 128 uints

  k_prep<<<256, 256, 0, stream>>>(x, xr, accs, bar);
  k_vmd<<<NBLK, 256, 0, stream>>>(xr, accs, bar, xl_s);
  k_tout<<<256, 256, 0, stream>>>(x, xl_s, out_xh, out_xl);
}

// Round 8
// 193.729 us; speedup vs baseline: 1.3992x; 1.3992x over previous
//
#include <hip/hip_runtime.h>

#define TLEN 2048
#define T2   4096
#define H2   2048
#define NBLK 256          // 2 channels/block, 1 block/CU (co-residency provable)
#define EPS32 1.1920928955078125e-07
#define TOLV 5e-5
#define A0   (-1.5339807878856412e-3f)   // -2*pi/4096
// bijective LDS swizzle: stride-16 writes and stride-256 reads conflict-free
#define PHI(i) ((i) ^ (((i) >> 4) & 15))

// accs layout (doubles): bkt[(it*16+b)*16 + i] for i<9 ; root at 1024 + it*16 + i
// bar  layout (uints):   bcnt[(it*16+b)*16] ; rdone 1024+it*16 ; flag 1088+it*16

__device__ __forceinline__ float2 cmulf(float2 a, float2 b){
  return make_float2(a.x * b.x - a.y * b.y, a.x * b.y + a.y * b.x);
}

// radix-4 butterfly in regs; s=+1 forward (W4=-i), s=-1 inverse (W4=+i)
__device__ __forceinline__ void dft4(float2& x0, float2& x1, float2& x2, float2& x3, float s){
  float t0x = x0.x + x2.x, t0y = x0.y + x2.y;
  float t1x = x0.x - x2.x, t1y = x0.y - x2.y;
  float t2x = x1.x + x3.x, t2y = x1.y + x3.y;
  float t3x = x1.x - x3.x, t3y = x1.y - x3.y;
  float r3x = s * t3y, r3y = -s * t3x;        // (-i*s) * t3
  x0 = make_float2(t0x + t2x, t0y + t2y);
  x1 = make_float2(t1x + r3x, t1y + r3y);
  x2 = make_float2(t0x - t2x, t0y - t2y);
  x3 = make_float2(t1x - r3x, t1y - r3y);
}

// 16-point FFT in regs; input natural v[m], output X[u0+4*u1] in v[4*u0+u1]
__device__ __forceinline__ void fft16r(float2* v, float s){
  const float C[10] = {1.f, 0.92387953251128674f, 0.70710678118654752f, 0.38268343236508977f,
                       0.f, 0.f, -0.70710678118654752f, 0.f, 0.f, -0.92387953251128674f};
  const float S[10] = {0.f, -0.38268343236508977f, -0.70710678118654752f, -0.92387953251128674f,
                       -1.f, 0.f, -0.70710678118654752f, 0.f, 0.f, 0.38268343236508977f};
  #pragma unroll
  for (int m0 = 0; m0 < 4; ++m0) dft4(v[m0], v[4 + m0], v[8 + m0], v[12 + m0], s);
  #pragma unroll
  for (int u0 = 1; u0 < 4; ++u0)
    #pragma unroll
    for (int m0 = 1; m0 < 4; ++m0){
      int k = u0 * m0;
      v[(u0 << 2) + m0] = cmulf(v[(u0 << 2) + m0], make_float2(C[k], s * S[k]));
    }
  #pragma unroll
  for (int u0 = 0; u0 < 4; ++u0)
    dft4(v[u0 << 2], v[(u0 << 2) + 1], v[(u0 << 2) + 2], v[(u0 << 2) + 3], s);
}

// dual-channel in-place 4096-pt FFT: 3 radix-16 Stockham stages, read->sync->write->sync.
// Both channels interleaved (independent chains). Trailing __syncthreads included.
__device__ __forceinline__ void fft4096_dual(float2* b0, float2* b1, float s){
  const int tid = threadIdx.x;
  const float a0 = s * A0;
  float2 v0[16], v1[16];
  // ---- stage 0: p = tid, twiddle W^{u*tid} ----
  #pragma unroll
  for (int m = 0; m < 16; ++m){
    int r = PHI(tid + (m << 8)); v0[m] = b0[r]; v1[m] = b1[r];
  }
  fft16r(v0, s); fft16r(v1, s);
  __syncthreads();
  #pragma unroll
  for (int u0 = 0; u0 < 4; ++u0)
    #pragma unroll
    for (int u1 = 0; u1 < 4; ++u1){
      int u = u0 + (u1 << 2);
      float2 X0 = v0[(u0 << 2) + u1], X1 = v1[(u0 << 2) + u1];
      if (u){
        float ang = a0 * (float)(u * tid);       // |u*tid| <= 3825, exact fp32
        float cw = __cosf(ang), sw = __sinf(ang);
        X0 = make_float2(X0.x*cw - X0.y*sw, X0.x*sw + X0.y*cw);
        X1 = make_float2(X1.x*cw - X1.y*sw, X1.x*sw + X1.y*cw);
      }
      int w = PHI((tid << 4) + u);
      b0[w] = X0; b1[w] = X1;
    }
  __syncthreads();
  // ---- stage 1: p = tid>>4, q = tid&15, twiddle W^{16*u*p} ----
  #pragma unroll
  for (int m = 0; m < 16; ++m){
    int r = PHI(tid + (m << 8)); v0[m] = b0[r]; v1[m] = b1[r];
  }
  fft16r(v0, s); fft16r(v1, s);
  __syncthreads();
  {
    const int p = tid >> 4, q = tid & 15;
    const float a1 = a0 * 16.0f;
    #pragma unroll
    for (int u0 = 0; u0 < 4; ++u0)
      #pragma unroll
      for (int u1 = 0; u1 < 4; ++u1){
        int u = u0 + (u1 << 2);
        float2 X0 = v0[(u0 << 2) + u1], X1 = v1[(u0 << 2) + u1];
        if (u){
          float ang = a1 * (float)(u * p);       // |u*p| <= 225
          float cw = __cosf(ang), sw = __sinf(ang);
          X0 = make_float2(X0.x*cw - X0.y*sw, X0.x*sw + X0.y*cw);
          X1 = make_float2(X1.x*cw - X1.y*sw, X1.x*sw + X1.y*cw);
        }
        int w = PHI(q + (((p << 4) + u) << 4));
        b0[w] = X0; b1[w] = X1;
      }
  }
  __syncthreads();
  // ---- stage 2: no twiddle ----
  #pragma unroll
  for (int m = 0; m < 16; ++m){
    int r = PHI(tid + (m << 8)); v0[m] = b0[r]; v1[m] = b1[r];
  }
  fft16r(v0, s); fft16r(v1, s);
  __syncthreads();
  #pragma unroll
  for (int u0 = 0; u0 < 4; ++u0)
    #pragma unroll
    for (int u1 = 0; u1 < 4; ++u1){
      int u = u0 + (u1 << 2);
      int w = PHI(tid + (u << 8));
      b0[w] = v0[(u0 << 2) + u1]; b1[w] = v1[(u0 << 2) + u1];
    }
  __syncthreads();
}

// ---- prep: coalesced transpose x:(B,T,C)->(c,t); zero stats + barrier words ----
__global__ void k_prep(const float* __restrict__ x, float* __restrict__ xr,
                       double* __restrict__ accs, unsigned* __restrict__ bar){
  const int blk = blockIdx.x, tid = threadIdx.x;
  if (blk < 5){
    int i = blk * 256 + tid; if (i < 1088) accs[i] = 0.0;
  } else if (blk < 10){
    int i = (blk - 5) * 256 + tid; if (i < 1152) bar[i] = 0u;
  }
  __shared__ float tile[64][65];
  const int b  = blk >> 5;
  const int t0 = (blk & 31) << 6;
  const int lo = tid & 63, r0 = tid >> 6;
  for (int pass = 0; pass < 16; ++pass){
    int tt = r0 + (pass << 2);
    tile[tt][lo] = x[((size_t)(b * TLEN + t0 + tt)) * 64 + lo];  // lo = ch, coalesced
  }
  __syncthreads();
  for (int pass = 0; pass < 16; ++pass){
    int c2 = r0 + (pass << 2);
    xr[((size_t)(b * 64 + c2)) * TLEN + t0 + lo] = tile[lo][c2]; // lo = t, coalesced
  }
}

// ---- fused VMD: dual fwd FFT + 5 iterations (u,F in VGPRs) + dual IFFT ----
// 256 blocks x 256 thr x ~66KB LDS = 1 block/CU -> unconditional co-residency.
__launch_bounds__(256, 1)
__global__ void k_vmd(const float* __restrict__ xr,
                      double* __restrict__ accs, unsigned* __restrict__ bar,
                      float* __restrict__ xl_s){
  __shared__ float2 buf0[T2];
  __shared__ float2 buf1[T2];
  __shared__ double red[40];
  __shared__ int sLast;
  const int tid = threadIdx.x;
  const int wave = tid >> 6, lane = tid & 63;
  const int c0 = blockIdx.x * 2, c1 = c0 + 1;
  const int bucket = blockIdx.x >> 4;          // 16 buckets x 16 blocks

  // ---- mirror-extend load (both channels) + dual forward FFT ----
  {
    const float* f0 = xr + (size_t)c0 * TLEN;
    const float* f1 = xr + (size_t)c1 * TLEN;
    #pragma unroll
    for (int pp = 0; pp < 16; ++pp){
      int i = tid + (pp << 8);
      int sidx = (i < 1024) ? (1023 - i) : ((i < 3072) ? (i - 1024) : (5119 - i));
      int d = PHI(i);
      buf0[d] = make_float2(f0[sidx], 0.0f);
      buf1[d] = make_float2(f1[sidx], 0.0f);
    }
  }
  __syncthreads();
  fft4096_dual(buf0, buf1, 1.0f);
  float2 F0[8], F1[8];
  #pragma unroll
  for (int pp = 0; pp < 8; ++pp){
    int r = PHI(tid + (pp << 8)); F0[pp] = buf0[r]; F1[pp] = buf1[r];
  }

  // ---- VMD state in registers: u[ch][mode][pp] ----
  float2 u[2][4][8];
  #pragma unroll
  for (int s = 0; s < 2; ++s)
    #pragma unroll
    for (int k = 0; k < 4; ++k)
      #pragma unroll
      for (int pp = 0; pp < 8; ++pp) u[s][k][pp] = make_float2(0.f, 0.f);

  float om[4] = {0.0f, 0.125f, 0.25f, 0.375f};
  bool active = true;

  for (int it = 0; it < 4; ++it){         // reference iterations 1..4 (with stats)
    if (active){
      double aFP[4] = {0,0,0,0}, aP[4] = {0,0,0,0}, aD = 0.0;
      #pragma unroll
      for (int s = 0; s < 2; ++s){
        #pragma unroll
        for (int pp = 0; pp < 8; ++pp){
          int j = tid + (pp << 8);
          float fj = (float)j * (1.0f / 4096.0f);
          float Fx = s ? F1[pp].x : F0[pp].x;
          float Fy = s ? F1[pp].y : F0[pp].y;
          float sx = u[s][0][pp].x + u[s][1][pp].x + u[s][2][pp].x + u[s][3][pp].x;
          float sy = u[s][0][pp].y + u[s][1][pp].y + u[s][2][pp].y + u[s][3][pp].y;
          #pragma unroll
          for (int k = 0; k < 4; ++k){
            float ox = sx - u[s][k][pp].x, oy = sy - u[s][k][pp].y;
            float d = fj - om[k];
            float den = 1.0f + 2000.0f * d * d;
            float nx = (Fx - ox) / den, ny = (Fy - oy) / den;
            float pw = nx * nx + ny * ny;
            aFP[k] += (double)(fj * pw);
            aP[k]  += (double)pw;
            float ddx = nx - u[s][k][pp].x, ddy = ny - u[s][k][pp].y;
            aD += (double)(ddx * ddx + ddy * ddy);
            u[s][k][pp] = make_float2(nx, ny);
            sx = ox + nx; sy = oy + ny;
          }
        }
      }
      double acc9[9] = {aFP[0],aFP[1],aFP[2],aFP[3],aP[0],aP[1],aP[2],aP[3],aD};
      #pragma unroll
      for (int i = 0; i < 9; ++i){
        double v = acc9[i];
        for (int off = 32; off; off >>= 1) v += __shfl_down(v, off);
        if (lane == 0) red[i * 4 + wave] = v;
      }
      __syncthreads();
      if (tid < 9)        // bucket-level add: 16 same-address RMWs, 16 lines parallel
        atomicAdd(&accs[(it * 16 + bucket) * 16 + tid],
                  red[tid*4+0] + red[tid*4+1] + red[tid*4+2] + red[tid*4+3]);
    }
    // ---- tree grid-barrier (always; `active` is grid-uniform) ----
    if (tid == 0){
      __threadfence();    // wave-level vmcnt drain covers lanes 1-8's bucket adds
      unsigned old = __hip_atomic_fetch_add(&bar[(it * 16 + bucket) * 16], 1u,
                                            __ATOMIC_ACQ_REL, __HIP_MEMORY_SCOPE_AGENT);
      sLast = (old == 15u) ? 1 : 0;
    }
    __syncthreads();
    if (sLast && tid < 9){                // bucket-last folds bucket -> root (parallel)
      double bv = __hip_atomic_load(&accs[(it * 16 + bucket) * 16 + tid],
                                    __ATOMIC_RELAXED, __HIP_MEMORY_SCOPE_AGENT);
      atomicAdd(&accs[1024 + it * 16 + tid], bv);
    }
    if (tid == 0){
      if (sLast){
        __threadfence();  // drain lanes' root adds before signaling
        unsigned old2 = __hip_atomic_fetch_add(&bar[1024 + it * 16], 1u,
                                               __ATOMIC_ACQ_REL, __HIP_MEMORY_SCOPE_AGENT);
        if (old2 == 15u)
          __hip_atomic_store(&bar[1088 + it * 16], 1u,
                             __ATOMIC_RELEASE, __HIP_MEMORY_SCOPE_AGENT);
      }
      while (__hip_atomic_load(&bar[1088 + it * 16], __ATOMIC_ACQUIRE,
                               __HIP_MEMORY_SCOPE_AGENT) == 0u)
        __builtin_amdgcn_s_sleep(2);
    }
    __syncthreads();
    if (active){
      if (tid < 9)
        red[tid] = __hip_atomic_load(&accs[1024 + it * 16 + tid],
                                     __ATOMIC_RELAXED, __HIP_MEMORY_SCOPE_AGENT);
      __syncthreads();
      #pragma unroll
      for (int k = 0; k < 4; ++k) om[k] = (float)(red[k] / red[4 + k]);
      double ud = red[8] * (1.0 / 4096.0) + EPS32;
      active = (ud > TOLV);
    }
    __syncthreads();
  }

  // ---- reference iteration 5: only mode-0 matters downstream ----
  if (active){
    #pragma unroll
    for (int s = 0; s < 2; ++s){
      #pragma unroll
      for (int pp = 0; pp < 8; ++pp){
        int j = tid + (pp << 8);
        float fj = (float)j * (1.0f / 4096.0f);
        float Fx = s ? F1[pp].x : F0[pp].x;
        float Fy = s ? F1[pp].y : F0[pp].y;
        float ox = u[s][1][pp].x + u[s][2][pp].x + u[s][3][pp].x;
        float oy = u[s][1][pp].y + u[s][2][pp].y + u[s][3][pp].y;
        float d = fj - om[0];
        float den = 1.0f + 2000.0f * d * d;
        u[s][0][pp] = make_float2((Fx - ox) / den, (Fy - oy) / den);
      }
    }
  }

  // ---- Hermitian build (reference quirks) + dual inverse FFT ----
  __syncthreads();
  #pragma unroll
  for (int pp = 0; pp < 8; ++pp){
    int j = tid + (pp << 8);
    float2 v0 = u[0][0][pp], v1 = u[1][0][pp];
    if (j == 0){
      buf0[PHI(0)] = make_float2(v0.x, -v0.y);        // S[0] = conj(U[0])
      buf1[PHI(0)] = make_float2(v1.x, -v1.y);
    } else {
      int a = PHI(j), bidx = PHI(T2 - j);
      buf0[a] = v0;  buf0[bidx] = make_float2(v0.x, -v0.y);   // S[4096-j]=conj(U[j])
      buf1[a] = v1;  buf1[bidx] = make_float2(v1.x, -v1.y);
    }
    if (j == H2 - 1){                                  // S[2048] = conj(U[2047])
      buf0[PHI(H2)] = make_float2(v0.x, -v0.y);
      buf1[PHI(H2)] = make_float2(v1.x, -v1.y);
    }
  }
  __syncthreads();
  fft4096_dual(buf0, buf1, -1.0f);
  const float scale = 1.0f / (float)T2;
  float* o0 = xl_s + (size_t)c0 * TLEN;
  float* o1 = xl_s + (size_t)c1 * TLEN;
  #pragma unroll
  for (int pp = 0; pp < 8; ++pp){
    int t = tid + (pp << 8);
    int r = PHI(1024 + t);
    o0[t] = buf0[r].x * scale;
    o1[t] = buf1[r].x * scale;
  }
}

// ---- transpose back + x_h = x - x_l ----
__global__ void k_tout(const float* __restrict__ x, const float* __restrict__ xl_s,
                       float* __restrict__ xh, float* __restrict__ xl){
  __shared__ float tile[64][65];
  int blk = blockIdx.x;
  int b  = blk >> 5;
  int t0 = (blk & 31) << 6;
  int lo = threadIdx.x & 63;
  int r0 = threadIdx.x >> 6;
  for (int pass = 0; pass < 16; ++pass){
    int c2 = r0 + (pass << 2);
    tile[c2][lo] = xl_s[((size_t)(b * 64 + c2)) * TLEN + t0 + lo];
  }
  __syncthreads();
  for (int pass = 0; pass < 16; ++pass){
    int tt = r0 + (pass << 2);
    size_t oi = ((size_t)(b * TLEN + t0 + tt)) * 64 + lo;
    float xlv = tile[lo][tt];
    float xv  = x[oi];
    xh[oi] = xv - xlv;
    xl[oi] = xlv;
  }
}

extern "C" void kernel_launch(void* const* d_in, const int* in_sizes, int n_in,
                              void* d_out, int out_size, void* d_ws, size_t ws_size,
                              hipStream_t stream){
  const float* x = (const float*)d_in[0];
  float* out_xh = (float*)d_out;
  float* out_xl = out_xh + (size_t)8 * TLEN * 64;

  char* ws = (char*)d_ws;
  float*    xr   = (float*)ws;                               // 4 MiB
  float*    xl_s = (float*)(ws + ((size_t)4 << 20));         // 4 MiB
  double*   accs = (double*)(ws + ((size_t)8 << 20));        // 1088 doubles
  unsigned* bar  = (unsigned*)(ws + ((size_t)8 << 20) + 16384); // 1152 uints

  k_prep<<<256, 256, 0, stream>>>(x, xr, accs, bar);
  k_vmd<<<NBLK, 256, 0, stream>>>(xr, accs, bar, xl_s);
  k_tout<<<256, 256, 0, stream>>>(x, xl_s, out_xh, out_xl);
}

// Round 9
// 157.824 us; speedup vs baseline: 1.7175x; 1.2275x over previous
//
#include <hip/hip_runtime.h>

#define TLEN 2048
#define T2   4096
#define H2   2048
#define EPS32 1.1920928955078125e-07
#define TOLV 5e-5
#define A0   (-1.5339807878856412e-3f)   // -2*pi/4096
// bijective LDS swizzle: stride-16 writes / stride-256 reads conflict-light
#define PHI(i) ((i) ^ (((i) >> 4) & 15))

// accs (doubles): set i = stats of reference iteration i+1, i in 0..3:
//   accs[i*256 + bucket*16 + j], bucket 0..15, j 0..8
//   j: 0-3 sum(fj*|u_k|^2), 4-7 sum(|u_k|^2), 8 sum(|du|^2)
// Consumers fold the 16 buckets in a fixed order -> identical fp64 everywhere.

__device__ __forceinline__ float2 cmulf(float2 a, float2 b){
  return make_float2(a.x * b.x - a.y * b.y, a.x * b.y + a.y * b.x);
}

// radix-4 butterfly in regs; s=+1 forward (W4=-i), s=-1 inverse (W4=+i)
__device__ __forceinline__ void dft4(float2& x0, float2& x1, float2& x2, float2& x3, float s){
  float t0x = x0.x + x2.x, t0y = x0.y + x2.y;
  float t1x = x0.x - x2.x, t1y = x0.y - x2.y;
  float t2x = x1.x + x3.x, t2y = x1.y + x3.y;
  float t3x = x1.x - x3.x, t3y = x1.y - x3.y;
  float r3x = s * t3y, r3y = -s * t3x;        // (-i*s) * t3
  x0 = make_float2(t0x + t2x, t0y + t2y);
  x1 = make_float2(t1x + r3x, t1y + r3y);
  x2 = make_float2(t0x - t2x, t0y - t2y);
  x3 = make_float2(t1x - r3x, t1y - r3y);
}

// 16-point FFT in regs; input natural v[m], output X[u0+4*u1] in v[4*u0+u1]
__device__ __forceinline__ void fft16r(float2* v, float s){
  const float C[10] = {1.f, 0.92387953251128674f, 0.70710678118654752f, 0.38268343236508977f,
                       0.f, 0.f, -0.70710678118654752f, 0.f, 0.f, -0.92387953251128674f};
  const float S[10] = {0.f, -0.38268343236508977f, -0.70710678118654752f, -0.92387953251128674f,
                       -1.f, 0.f, -0.70710678118654752f, 0.f, 0.f, 0.38268343236508977f};
  #pragma unroll
  for (int m0 = 0; m0 < 4; ++m0) dft4(v[m0], v[4 + m0], v[8 + m0], v[12 + m0], s);
  #pragma unroll
  for (int u0 = 1; u0 < 4; ++u0)
    #pragma unroll
    for (int m0 = 1; m0 < 4; ++m0){
      int k = u0 * m0;
      v[(u0 << 2) + m0] = cmulf(v[(u0 << 2) + m0], make_float2(C[k], s * S[k]));
    }
  #pragma unroll
  for (int u0 = 0; u0 < 4; ++u0)
    dft4(v[u0 << 2], v[(u0 << 2) + 1], v[(u0 << 2) + 2], v[(u0 << 2) + 3], s);
}

// in-place 4096-pt FFT: 3 radix-16 Stockham stages over ONE 32 KB buffer
// (read 16 -> compute -> sync -> write 16 -> sync). PHI layout throughout.
__device__ __forceinline__ void fft4096_ip(float2* buf, float s){
  const int tid = threadIdx.x;
  const float a0 = s * A0;
  float2 v[16];
  // stage 0: p = tid, twiddle W^{u*tid}
  #pragma unroll
  for (int m = 0; m < 16; ++m) v[m] = buf[PHI(tid + (m << 8))];
  fft16r(v, s);
  __syncthreads();
  #pragma unroll
  for (int u0 = 0; u0 < 4; ++u0)
    #pragma unroll
    for (int u1 = 0; u1 < 4; ++u1){
      int u = u0 + (u1 << 2);
      float2 X = v[(u0 << 2) + u1];
      if (u){
        float ang = a0 * (float)(u * tid);       // |u*tid| <= 3825, exact fp32
        float cw = __cosf(ang), sw = __sinf(ang);
        X = make_float2(X.x*cw - X.y*sw, X.x*sw + X.y*cw);
      }
      buf[PHI((tid << 4) + u)] = X;
    }
  __syncthreads();
  // stage 1: p = tid>>4, q = tid&15, twiddle W^{16*u*p}
  #pragma unroll
  for (int m = 0; m < 16; ++m) v[m] = buf[PHI(tid + (m << 8))];
  fft16r(v, s);
  __syncthreads();
  {
    const int p = tid >> 4, q = tid & 15;
    const float a1 = a0 * 16.0f;
    #pragma unroll
    for (int u0 = 0; u0 < 4; ++u0)
      #pragma unroll
      for (int u1 = 0; u1 < 4; ++u1){
        int u = u0 + (u1 << 2);
        float2 X = v[(u0 << 2) + u1];
        if (u){
          float ang = a1 * (float)(u * p);       // |u*p| <= 225
          float cw = __cosf(ang), sw = __sinf(ang);
          X = make_float2(X.x*cw - X.y*sw, X.x*sw + X.y*cw);
        }
        buf[PHI(q + (((p << 4) + u) << 4))] = X;
      }
  }
  __syncthreads();
  // stage 2: no twiddle
  #pragma unroll
  for (int m = 0; m < 16; ++m) v[m] = buf[PHI(tid + (m << 8))];
  fft16r(v, s);
  __syncthreads();
  #pragma unroll
  for (int u0 = 0; u0 < 4; ++u0)
    #pragma unroll
    for (int u1 = 0; u1 < 4; ++u1){
      int u = u0 + (u1 << 2);
      buf[PHI(tid + (u << 8))] = v[(u0 << 2) + u1];
    }
  __syncthreads();
}

// per-bin 4-mode Gauss-Seidel chain (no stats) — must match vmd_bin's u-path
__device__ __forceinline__ void vmd_chain(float Fx, float Fy, float fj,
                                          const float* om, float* ux, float* uy){
  float sx = ux[0] + ux[1] + ux[2] + ux[3];
  float sy = uy[0] + uy[1] + uy[2] + uy[3];
  #pragma unroll
  for (int k = 0; k < 4; ++k){
    float ox = sx - ux[k], oy = sy - uy[k];
    float d = fj - om[k];
    float den = 1.0f + 2000.0f * d * d;
    float nx = (Fx - ox) / den, ny = (Fy - oy) / den;
    ux[k] = nx; uy[k] = ny;
    sx = ox + nx; sy = oy + ny;
  }
}

// same chain, with stats
__device__ __forceinline__ void vmd_bin(float Fx, float Fy, float fj,
                                        const float* om, float* ux, float* uy,
                                        double* aFP, double* aP, double& aD){
  float sx = ux[0] + ux[1] + ux[2] + ux[3];
  float sy = uy[0] + uy[1] + uy[2] + uy[3];
  #pragma unroll
  for (int k = 0; k < 4; ++k){
    float ox = sx - ux[k], oy = sy - uy[k];
    float d = fj - om[k];
    float den = 1.0f + 2000.0f * d * d;
    float nx = (Fx - ox) / den, ny = (Fy - oy) / den;
    float pw = nx * nx + ny * ny;
    aFP[k] += (double)(fj * pw);
    aP[k]  += (double)pw;
    float ddx = nx - ux[k], ddy = ny - uy[k];
    aD += (double)(ddx * ddx + ddy * ddy);
    ux[k] = nx; uy[k] = ny;
    sx = ox + nx; sy = oy + ny;
  }
}

// block-reduce 9 doubles -> atomicAdd into dst[0..8] (one bucket line)
__device__ __forceinline__ void reduce9_to(double* acc, double* red, double* dst){
  const int tid = threadIdx.x, wave = tid >> 6, lane = tid & 63;
  #pragma unroll
  for (int i = 0; i < 9; ++i){
    double v = acc[i];
    for (int off = 32; off; off >>= 1) v += __shfl_down(v, off);
    if (lane == 0) red[i * 4 + wave] = v;
  }
  __syncthreads();
  if (tid < 9)
    atomicAdd(&dst[tid], red[tid*4+0] + red[tid*4+1] + red[tid*4+2] + red[tid*4+3]);
}

// ---- prep: coalesced transpose x:(B,T,C)->(c,t); zero accs ----
__global__ void k_prep(const float* __restrict__ x, float* __restrict__ xr,
                       double* __restrict__ accs){
  const int blk = blockIdx.x, tid = threadIdx.x;
  if (blk < 4) accs[blk * 256 + tid] = 0.0;    // 1024 doubles
  __shared__ float tile[64][65];
  const int b  = blk >> 5;
  const int t0 = (blk & 31) << 6;
  const int lo = tid & 63, r0 = tid >> 6;
  for (int pass = 0; pass < 16; ++pass){
    int tt = r0 + (pass << 2);
    tile[tt][lo] = x[((size_t)(b * TLEN + t0 + tt)) * 64 + lo];  // lo = ch, coalesced
  }
  __syncthreads();
  for (int pass = 0; pass < 16; ++pass){
    int c2 = r0 + (pass << 2);
    xr[((size_t)(b * 64 + c2)) * TLEN + t0 + lo] = tile[lo][c2]; // lo = t, coalesced
  }
}

// ---- forward FFT (in-place, 32 KB LDS) + iter-1 stats; F stored fp32 ----
__launch_bounds__(256, 1)
__global__ void k_fft1(const float* __restrict__ xr, float2* __restrict__ F,
                       double* __restrict__ accs){
  __shared__ float2 buf[T2];
  __shared__ double red[40];
  const int tid = threadIdx.x, c = blockIdx.x;
  const int bucket = blockIdx.x >> 5;          // 512 blocks -> 16 buckets
  {
    const float* f = xr + (size_t)c * TLEN;
    #pragma unroll
    for (int pp = 0; pp < 16; ++pp){
      int i = tid + (pp << 8);
      int s = (i < 1024) ? (1023 - i) : ((i < 3072) ? (i - 1024) : (5119 - i));
      buf[PHI(i)] = make_float2(f[s], 0.0f);
    }
  }
  __syncthreads();
  fft4096_ip(buf, 1.0f);
  float2 Fr[8];
  #pragma unroll
  for (int pp = 0; pp < 8; ++pp) Fr[pp] = buf[PHI(tid + (pp << 8))];
  #pragma unroll
  for (int pp = 0; pp < 8; ++pp) F[(size_t)c * H2 + tid + (pp << 8)] = Fr[pp];
  // reference iteration 1 (u starts at 0, initial omega)
  const float om[4] = {0.0f, 0.125f, 0.25f, 0.375f};
  double aFP[4] = {0,0,0,0}, aP[4] = {0,0,0,0}, aD = 0.0;
  #pragma unroll
  for (int pp = 0; pp < 8; ++pp){
    int j = tid + (pp << 8);
    float fj = (float)j * (1.0f / 4096.0f);
    float ux[4] = {0.f,0.f,0.f,0.f}, uy[4] = {0.f,0.f,0.f,0.f};
    vmd_bin(Fr[pp].x, Fr[pp].y, fj, om, ux, uy, aFP, aP, aD);
  }
  double acc9[9] = {aFP[0],aFP[1],aFP[2],aFP[3],aP[0],aP[1],aP[2],aP[3],aD};
  reduce9_to(acc9, red, accs + bucket * 16);
}

// ---- iteration NIT (2..4): fold prior stats, replay 1..NIT-1 from F, compute NIT ----
template<int NIT>
__launch_bounds__(256, 1)
__global__ void k_it(const float2* __restrict__ F, double* __restrict__ accs){
  __shared__ double sf[3][9];
  __shared__ double red[40];
  const int tid = threadIdx.x;
  const int c = blockIdx.x >> 1, half = blockIdx.x & 1;   // 1024 blocks, half-channel
  const int bucket = blockIdx.x >> 6;                      // 16 buckets
  if (tid < 9){
    #pragma unroll
    for (int p = 0; p < NIT - 1; ++p){
      double v = 0.0;
      #pragma unroll
      for (int b = 0; b < 16; ++b) v += accs[p * 256 + b * 16 + tid];
      sf[p][tid] = v;
    }
  }
  __syncthreads();
  if (sf[NIT - 2][4] == 0.0) return;                                  // prev never ran
  if (sf[NIT - 2][8] * (1.0 / 4096.0) + EPS32 <= TOLV) return;        // converged
  const size_t base = (size_t)c * H2 + (half << 10);
  float2 Fr[4];
  #pragma unroll
  for (int pp = 0; pp < 4; ++pp) Fr[pp] = F[base + tid + (pp << 8)];
  float ux[4][4], uy[4][4];
  #pragma unroll
  for (int pp = 0; pp < 4; ++pp)
    #pragma unroll
    for (int k = 0; k < 4; ++k){ ux[pp][k] = 0.f; uy[pp][k] = 0.f; }
  float om[4] = {0.0f, 0.125f, 0.25f, 0.375f};
  #pragma unroll
  for (int j = 1; j <= NIT - 1; ++j){          // replay iterations 1..NIT-1
    #pragma unroll
    for (int pp = 0; pp < 4; ++pp){
      int jb = (half << 10) + tid + (pp << 8);
      float fj = (float)jb * (1.0f / 4096.0f);
      vmd_chain(Fr[pp].x, Fr[pp].y, fj, om, ux[pp], uy[pp]);
    }
    #pragma unroll
    for (int k = 0; k < 4; ++k) om[k] = (float)(sf[j - 1][k] / sf[j - 1][4 + k]);
  }
  double aFP[4] = {0,0,0,0}, aP[4] = {0,0,0,0}, aD = 0.0;
  #pragma unroll
  for (int pp = 0; pp < 4; ++pp){              // iteration NIT with stats
    int jb = (half << 10) + tid + (pp << 8);
    float fj = (float)jb * (1.0f / 4096.0f);
    vmd_bin(Fr[pp].x, Fr[pp].y, fj, om, ux[pp], uy[pp], aFP, aP, aD);
  }
  double acc9[9] = {aFP[0],aFP[1],aFP[2],aFP[3],aP[0],aP[1],aP[2],aP[3],aD};
  reduce9_to(acc9, red, accs + (NIT - 1) * 256 + bucket * 16);
}

// ---- replay 1..4 + iteration-5 mode-0 + Hermitian build + in-place IFFT ----
__launch_bounds__(256, 1)
__global__ void k_ifft5(const float2* __restrict__ F, const double* __restrict__ accs,
                        float* __restrict__ xl_s){
  __shared__ float2 buf[T2];
  __shared__ double sf[4][9];
  const int tid = threadIdx.x, c = blockIdx.x;
  if (tid < 9){
    #pragma unroll
    for (int p = 0; p < 4; ++p){
      double v = 0.0;
      #pragma unroll
      for (int b = 0; b < 16; ++b) v += accs[p * 256 + b * 16 + tid];
      sf[p][tid] = v;
    }
  }
  __syncthreads();
  float2 Fr[8];
  #pragma unroll
  for (int pp = 0; pp < 8; ++pp) Fr[pp] = F[(size_t)c * H2 + tid + (pp << 8)];
  float ux[8][4], uy[8][4];
  #pragma unroll
  for (int pp = 0; pp < 8; ++pp)
    #pragma unroll
    for (int k = 0; k < 4; ++k){ ux[pp][k] = 0.f; uy[pp][k] = 0.f; }
  float om[4] = {0.0f, 0.125f, 0.25f, 0.375f};
  bool run5 = true;
  for (int it = 0; it < 4; ++it){              // replay iterations that ran
    if (sf[it][4] == 0.0){ run5 = false; break; }
    #pragma unroll
    for (int pp = 0; pp < 8; ++pp){
      int j = tid + (pp << 8);
      float fj = (float)j * (1.0f / 4096.0f);
      vmd_chain(Fr[pp].x, Fr[pp].y, fj, om, ux[pp], uy[pp]);
    }
    #pragma unroll
    for (int k = 0; k < 4; ++k) om[k] = (float)(sf[it][k] / sf[it][4 + k]);
    if (sf[it][8] * (1.0 / 4096.0) + EPS32 <= TOLV){ run5 = false; break; }
  }
  float2 u0[8];
  #pragma unroll
  for (int pp = 0; pp < 8; ++pp){
    if (run5){                                 // iter-5 mode-0: others still at iter-4
      int j = tid + (pp << 8);
      float fj = (float)j * (1.0f / 4096.0f);
      float ox = ux[pp][1] + ux[pp][2] + ux[pp][3];
      float oy = uy[pp][1] + uy[pp][2] + uy[pp][3];
      float d = fj - om[0];
      float den = 1.0f + 2000.0f * d * d;
      u0[pp] = make_float2((Fr[pp].x - ox) / den, (Fr[pp].y - oy) / den);
    } else {
      u0[pp] = make_float2(ux[pp][0], uy[pp][0]);
    }
  }
  // Hermitian build (reference's exact quirks), PHI layout
  #pragma unroll
  for (int pp = 0; pp < 8; ++pp){
    int j = tid + (pp << 8);
    float2 v = u0[pp];
    if (j == 0){
      buf[PHI(0)] = make_float2(v.x, -v.y);            // S[0] = conj(U[0])
    } else {
      buf[PHI(j)]      = v;                            // S[j] = U[j]
      buf[PHI(T2 - j)] = make_float2(v.x, -v.y);       // S[4096-j] = conj(U[j])
    }
    if (j == H2 - 1) buf[PHI(H2)] = make_float2(v.x, -v.y);  // S[2048] = conj(U[2047])
  }
  __syncthreads();
  fft4096_ip(buf, -1.0f);
  const float scale = 1.0f / (float)T2;
  #pragma unroll
  for (int pp = 0; pp < 8; ++pp){
    int t = tid + (pp << 8);
    xl_s[(size_t)c * TLEN + t] = buf[PHI(1024 + t)].x * scale;
  }
}

// ---- transpose back + x_h = x - x_l ----
__global__ void k_tout(const float* __restrict__ x, const float* __restrict__ xl_s,
                       float* __restrict__ xh, float* __restrict__ xl){
  __shared__ float tile[64][65];
  int blk = blockIdx.x;
  int b  = blk >> 5;
  int t0 = (blk & 31) << 6;
  int lo = threadIdx.x & 63;
  int r0 = threadIdx.x >> 6;
  for (int pass = 0; pass < 16; ++pass){
    int c2 = r0 + (pass << 2);
    tile[c2][lo] = xl_s[((size_t)(b * 64 + c2)) * TLEN + t0 + lo];
  }
  __syncthreads();
  for (int pass = 0; pass < 16; ++pass){
    int tt = r0 + (pass << 2);
    size_t oi = ((size_t)(b * TLEN + t0 + tt)) * 64 + lo;
    float xlv = tile[lo][tt];
    float xv  = x[oi];
    xh[oi] = xv - xlv;
    xl[oi] = xlv;
  }
}

extern "C" void kernel_launch(void* const* d_in, const int* in_sizes, int n_in,
                              void* d_out, int out_size, void* d_ws, size_t ws_size,
                              hipStream_t stream){
  const float* x = (const float*)d_in[0];
  float* out_xh = (float*)d_out;
  float* out_xl = out_xh + (size_t)8 * TLEN * 64;

  char* ws = (char*)d_ws;
  float*  xr   = (float*)ws;                           // 4 MiB
  float*  xl_s = (float*)(ws + ((size_t)4 << 20));     // 4 MiB
  float2* F    = (float2*)(ws + ((size_t)8 << 20));    // 8 MiB
  double* accs = (double*)(ws + ((size_t)16 << 20));   // 1024 doubles (4 bucket sets)

  k_prep<<<256, 256, 0, stream>>>(x, xr, accs);
  k_fft1<<<512, 256, 0, stream>>>(xr, F, accs);        // fwd FFT + iter 1
  k_it<2><<<1024, 256, 0, stream>>>(F, accs);          // iter 2 (replay 1)
  k_it<3><<<1024, 256, 0, stream>>>(F, accs);          // iter 3 (replay 1-2)
  k_it<4><<<1024, 256, 0, stream>>>(F, accs);          // iter 4 (replay 1-3)
  k_ifft5<<<512, 256, 0, stream>>>(F, accs, xl_s);     // replay 1-4 + iter 5 + IFFT
  k_tout<<<256, 256, 0, stream>>>(x, xl_s, out_xh, out_xl);
}